// Round 4
// baseline (2425.175 us; speedup 1.0000x reference)
//
#include <hip/hip_runtime.h>
#include <hip/hip_bf16.h>

#define TT 32
#define DD 128
#define HH 256
#define VV 32000
#define ZZ 256
#define NTL 50            // n-slabs for V-GEMM (50 x 640 = 32000)

typedef __attribute__((ext_vector_type(8))) short bf16x8;
typedef __attribute__((ext_vector_type(4))) float f32x4;

static __device__ inline unsigned short f2bf(float x) {
    __hip_bfloat16 h = __float2bfloat16(x);
    return *(unsigned short*)&h;
}

// ---------------- edges canonicalizer (bool-vs-int32 layout detect) ----------------
__global__ void edge_canon_k(const unsigned char* __restrict__ eb,
                             unsigned char* __restrict__ canon)
{
    __shared__ int flag;
    if (threadIdx.x == 0) flag = 0;
    __syncthreads();
    int acc = 0;
    for (int i = threadIdx.x; i < TT * DD; i += 256)
        if (i & 3) acc |= eb[i];
    if (acc) atomicOr(&flag, 1);
    __syncthreads();
    const bool is_i32 = (flag == 0);
    for (int i = threadIdx.x; i < TT * DD; i += 256)
        canon[i] = is_i32 ? eb[4 * (size_t)i] : eb[i];
}

// ---------------- pack f32 [nrow16*16][256] -> fragment-linear bf16 ----------------
// chunk i = (j*8 + ks)*64 + lane ; lane=(g,c) holds src[j*16+c][ks*32+g*8 .. +8]
__global__ __launch_bounds__(256) void pack_frag(
    const float* __restrict__ src, __hip_bfloat16* __restrict__ dst, int nchunks_total)
{
    int i = blockIdx.x * 256 + threadIdx.x;
    if (i >= nchunks_total) return;
    int lane = i & 63, ks = (i >> 6) & 7, j = i >> 9;
    int g = lane >> 4, c = lane & 15;
    const float* s = src + (size_t)(j * 16 + c) * HH + ks * 32 + g * 8;
    float4 v0 = *(const float4*)s;
    float4 v1 = *(const float4*)(s + 4);
    bf16x8 o;
    o[0] = (short)f2bf(v0.x); o[1] = (short)f2bf(v0.y);
    o[2] = (short)f2bf(v0.z); o[3] = (short)f2bf(v0.w);
    o[4] = (short)f2bf(v1.x); o[5] = (short)f2bf(v1.y);
    o[6] = (short)f2bf(v1.z); o[7] = (short)f2bf(v1.w);
    *(bf16x8*)(dst + (size_t)i * 8) = o;
}

// ---------------- gather emb rows by token -> packed fragment A [4096][256] ----------------
__global__ __launch_bounds__(256) void gather_pack(
    const int* __restrict__ nodes, const float* __restrict__ emb,
    __hip_bfloat16* __restrict__ dst)
{
    int i = blockIdx.x * 256 + threadIdx.x;      // 131072 chunks
    int lane = i & 63, ks = (i >> 6) & 7, j = i >> 9;
    int g = lane >> 4, c = lane & 15;
    int row = j * 16 + c;
    int tok = nodes[row];
    const float* s = emb + (size_t)tok * HH + ks * 32 + g * 8;
    float4 v0 = *(const float4*)s;
    float4 v1 = *(const float4*)(s + 4);
    bf16x8 o;
    o[0] = (short)f2bf(v0.x); o[1] = (short)f2bf(v0.y);
    o[2] = (short)f2bf(v0.z); o[3] = (short)f2bf(v0.w);
    o[4] = (short)f2bf(v1.x); o[5] = (short)f2bf(v1.y);
    o[6] = (short)f2bf(v1.z); o[7] = (short)f2bf(v1.w);
    *(bf16x8*)(dst + (size_t)i * 8) = o;
}

// ============ register-stationary GEMM, packed operands ============
// A, B in fragment-linear layout. C row-major [4096][ldc] fp32.
// Block = 4 waves; wave owns 16 m-rows. Grid (64 m, ntiles slabs), m-fastest.
template<bool WRITE_C, bool HAS_BIAS, bool LSE_PARTIAL, bool LSE_SUB>
__global__ __launch_bounds__(256, 4) void gemm_rs(
    const __hip_bfloat16* __restrict__ A,
    const __hip_bfloat16* __restrict__ B,
    int ldc, int nchunks, int ntiles,
    const float* __restrict__ bias,
    const float* __restrict__ lse,
    float* __restrict__ C,
    float* __restrict__ pm, float* __restrict__ ps)
{
    __shared__ float lds_st[WRITE_C ? (4 * 16 * 68) : 1];

    const int tid  = threadIdx.x;
    const int w    = tid >> 6;
    const int lane = tid & 63;
    const int g    = lane >> 4;
    const int c    = lane & 15;
    const int m0   = blockIdx.x * 64;
    const int row16 = m0 + w * 16;
    const int n0   = blockIdx.y * (nchunks * 64);
    const int jb0  = n0 >> 4;                     // base n16-block of slab

    // A fragments, fully coalesced packed loads (1KB/instr)
    bf16x8 a[8];
    {
        const __hip_bfloat16* ap = A + (((size_t)(row16 >> 4) * 8) * 64 + lane) * 8;
#pragma unroll
        for (int ks = 0; ks < 8; ++ks) a[ks] = *(const bf16x8*)(ap + ks * 512);
    }

    float mrun[4], srun[4];
#pragma unroll
    for (int r = 0; r < 4; ++r) { mrun[r] = -3.0e38f; srun[r] = 0.f; }

    float lsev[4];
    if (LSE_SUB) {
#pragma unroll
        for (int r = 0; r < 4; ++r) lsev[r] = lse[row16 + 4 * g + r];
    }

    for (int nc = 0; nc < nchunks; ++nc) {
        const int nb = n0 + nc * 64;
        const __hip_bfloat16* bp = B + (((size_t)(jb0 + nc * 4) * 8) * 64 + lane) * 8;

        f32x4 acc[4];
#pragma unroll
        for (int nf = 0; nf < 4; ++nf) acc[nf] = (f32x4){0.f, 0.f, 0.f, 0.f};

#pragma unroll
        for (int ks = 0; ks < 8; ++ks) {
            bf16x8 b0 = *(const bf16x8*)(bp + (0 * 8 + ks) * 512);
            bf16x8 b1 = *(const bf16x8*)(bp + (1 * 8 + ks) * 512);
            bf16x8 b2 = *(const bf16x8*)(bp + (2 * 8 + ks) * 512);
            bf16x8 b3 = *(const bf16x8*)(bp + (3 * 8 + ks) * 512);
            acc[0] = __builtin_amdgcn_mfma_f32_16x16x32_bf16(a[ks], b0, acc[0], 0, 0, 0);
            acc[1] = __builtin_amdgcn_mfma_f32_16x16x32_bf16(a[ks], b1, acc[1], 0, 0, 0);
            acc[2] = __builtin_amdgcn_mfma_f32_16x16x32_bf16(a[ks], b2, acc[2], 0, 0, 0);
            acc[3] = __builtin_amdgcn_mfma_f32_16x16x32_bf16(a[ks], b3, acc[3], 0, 0, 0);
        }

        float bv[4] = {0.f, 0.f, 0.f, 0.f};
        if (HAS_BIAS) {
#pragma unroll
            for (int nf = 0; nf < 4; ++nf) bv[nf] = bias[nb + nf * 16 + c];
        }

        if (LSE_PARTIAL) {
#pragma unroll
            for (int r = 0; r < 4; ++r) {
                float l0 = acc[0][r] + bv[0];
                float l1 = acc[1][r] + bv[1];
                float l2 = acc[2][r] + bv[2];
                float l3 = acc[3][r] + bv[3];
                float mc = fmaxf(fmaxf(l0, l1), fmaxf(l2, l3));
                float mn = fmaxf(mrun[r], mc);
                srun[r] = srun[r] * __expf(mrun[r] - mn)
                        + __expf(l0 - mn) + __expf(l1 - mn)
                        + __expf(l2 - mn) + __expf(l3 - mn);
                mrun[r] = mn;
            }
        }

        if (WRITE_C) {
            const int base = w * (16 * 68);
#pragma unroll
            for (int nf = 0; nf < 4; ++nf)
#pragma unroll
                for (int r = 0; r < 4; ++r) {
                    float v = acc[nf][r] + bv[nf];
                    if (LSE_SUB) v -= lsev[r];
                    lds_st[base + (4 * g + r) * 68 + nf * 16 + c] = v;
                }
#pragma unroll
            for (int i = 0; i < 4; ++i) {
                int lr = i * 4 + g;
                float4 v = *(const float4*)&lds_st[base + lr * 68 + c * 4];
                *(float4*)(C + (size_t)(row16 + lr) * ldc + nb + c * 4) = v;
            }
        }
    }

    if (LSE_PARTIAL) {
#pragma unroll
        for (int r = 0; r < 4; ++r) {
            float m = mrun[r], s = srun[r];
#pragma unroll
            for (int mk = 1; mk <= 8; mk <<= 1) {
                float m2 = __shfl_xor(m, mk);
                float s2 = __shfl_xor(s, mk);
                float mn = fmaxf(m, m2);
                s = s * __expf(m - mn) + s2 * __expf(m2 - mn);
                m = mn;
            }
            if (c == 0) {
                int row = row16 + 4 * g + r;
                pm[(size_t)row * ntiles + blockIdx.y] = m;
                ps[(size_t)row * ntiles + blockIdx.y] = s;
            }
        }
    }
}

// ---------------- GRU recurrent step v4: d-group of 8, both-variant select ----------------
// grid (8 j-tiles, 16 d-groups), block 256 = (jl 32 x kq 8)
__global__ __launch_bounds__(256) void gru_step4(
    const unsigned char* __restrict__ edges_t,
    const float* __restrict__ gi_t, int phase_off,
    const float* __restrict__ Whh_c, const float* __restrict__ bih_c,
    const float* __restrict__ bhh_c,
    const float* __restrict__ Whh_s, const float* __restrict__ bih_s,
    const float* __restrict__ bhh_s,
    const float* __restrict__ h_in, float* __restrict__ h_out,
    __hip_bfloat16* __restrict__ outs_packed, int t)
{
    const int jl = threadIdx.x >> 3;
    const int kq = threadIdx.x & 7;
    const int j  = blockIdx.x * 32 + jl;
    const int d0 = blockIdx.y * 8;

    bool e[8];
#pragma unroll
    for (int dd = 0; dd < 8; ++dd) e[dd] = edges_t[d0 + dd] != 0;

    const float4* __restrict__ wcr = (const float4*)(Whh_c + (size_t)j * HH);
    const float4* __restrict__ wcz = (const float4*)(Whh_c + (size_t)(j + HH) * HH);
    const float4* __restrict__ wcn = (const float4*)(Whh_c + (size_t)(j + 2 * HH) * HH);
    const float4* __restrict__ wsr = (const float4*)(Whh_s + (size_t)j * HH);
    const float4* __restrict__ wsz = (const float4*)(Whh_s + (size_t)(j + HH) * HH);
    const float4* __restrict__ wsn = (const float4*)(Whh_s + (size_t)(j + 2 * HH) * HH);

    float sr[8], sz[8], sn[8];
#pragma unroll
    for (int dd = 0; dd < 8; ++dd) { sr[dd] = 0.f; sz[dd] = 0.f; sn[dd] = 0.f; }

#pragma unroll
    for (int i = 0; i < 8; ++i) {
        const int f = i * 8 + kq;
        float4 cr = wcr[f], cz = wcz[f], cn = wcn[f];
        float4 vr = wsr[f], vz = wsz[f], vn = wsn[f];
#pragma unroll
        for (int dd = 0; dd < 8; ++dd) {
            float4 hv = ((const float4*)(h_in + (size_t)(d0 + dd) * HH))[f];
            float4 wr_ = e[dd] ? cr : vr;
            float4 wz_ = e[dd] ? cz : vz;
            float4 wn_ = e[dd] ? cn : vn;
            sr[dd] += hv.x * wr_.x + hv.y * wr_.y + hv.z * wr_.z + hv.w * wr_.w;
            sz[dd] += hv.x * wz_.x + hv.y * wz_.y + hv.z * wz_.z + hv.w * wz_.w;
            sn[dd] += hv.x * wn_.x + hv.y * wn_.y + hv.z * wn_.z + hv.w * wn_.w;
        }
    }
#pragma unroll
    for (int dd = 0; dd < 8; ++dd) {
        sr[dd] += __shfl_xor(sr[dd], 1); sr[dd] += __shfl_xor(sr[dd], 2); sr[dd] += __shfl_xor(sr[dd], 4);
        sz[dd] += __shfl_xor(sz[dd], 1); sz[dd] += __shfl_xor(sz[dd], 2); sz[dd] += __shfl_xor(sz[dd], 4);
        sn[dd] += __shfl_xor(sn[dd], 1); sn[dd] += __shfl_xor(sn[dd], 2); sn[dd] += __shfl_xor(sn[dd], 4);
    }

    if (kq == 0) {
#pragma unroll
        for (int dd = 0; dd < 8; ++dd) {
            const int d = d0 + dd;
            const float* __restrict__ bih = e[dd] ? bih_c : bih_s;
            const float* __restrict__ bhh = e[dd] ? bhh_c : bhh_s;
            const float* __restrict__ gi  = gi_t + (size_t)d * 3072 + phase_off + (e[dd] ? 0 : 768);
            float ir  = gi[j]          + bih[j];
            float iz  = gi[j + HH]     + bih[j + HH];
            float in_ = gi[j + 2 * HH] + bih[j + 2 * HH];
            float hr = sr[dd] + bhh[j];
            float hz = sz[dd] + bhh[j + HH];
            float hn = sn[dd] + bhh[j + 2 * HH];
            float rg = 1.f / (1.f + __expf(-(ir + hr)));
            float zg = 1.f / (1.f + __expf(-(iz + hz)));
            float nn = tanhf(in_ + rg * hn);
            float hprev = h_in[(size_t)d * HH + j];
            float hnew = (1.f - zg) * nn + zg * hprev;
            h_out[(size_t)d * HH + j] = hnew;
            if (outs_packed) {
                // packed-fragment index for row = t*128+d, element k = j
                size_t idx = ((((size_t)t * 8 + (d >> 4)) * 8 + (j >> 5)) * 64
                              + ((j >> 3) & 3) * 16 + (d & 15)) * 8 + (j & 7);
                outs_packed[idx] = __float2bfloat16(hnew);
            }
        }
    }
}

// ---------------- latent head ----------------
__global__ __launch_bounds__(256) void latent_k(
    const float* __restrict__ hid, const float* __restrict__ W_mean,
    const float* __restrict__ b_mean, const float* __restrict__ W_logv,
    const float* __restrict__ b_logv, const float* __restrict__ eps,
    float* __restrict__ out_mean, float* __restrict__ out_logv,
    float* __restrict__ out_z)
{
    int idx = blockIdx.x * blockDim.x + threadIdx.x;  // D*Z = 32768
    int d = idx >> 8, zi = idx & 255;
    const float4* hv = (const float4*)(hid + (size_t)d * HH);
    const float4* wm = (const float4*)(W_mean + (size_t)zi * HH);
    const float4* wl = (const float4*)(W_logv + (size_t)zi * HH);
    float sm = 0.f, sl = 0.f;
#pragma unroll 8
    for (int k = 0; k < HH / 4; ++k) {
        float4 h4 = hv[k], m4 = wm[k], l4 = wl[k];
        sm += h4.x * m4.x + h4.y * m4.y + h4.z * m4.z + h4.w * m4.w;
        sl += h4.x * l4.x + h4.y * l4.y + h4.z * l4.z + h4.w * l4.w;
    }
    float mean = sm + b_mean[zi];
    float logv = sl + b_logv[zi];
    float zval = eps[idx] * expf(0.5f * logv) + mean;
    out_mean[idx] = mean;
    out_logv[idx] = logv;
    out_z[idx]    = zval;
}

// ---------------- h0 = z @ W_l2h.T + b ----------------
__global__ __launch_bounds__(256) void h0_k(
    const float* __restrict__ z, const float* __restrict__ W_l2h,
    const float* __restrict__ b_l2h, float* __restrict__ h0)
{
    int idx = blockIdx.x * blockDim.x + threadIdx.x;  // D*H = 32768
    int d = idx >> 8, j = idx & 255;
    const float4* zv = (const float4*)(z + (size_t)d * ZZ);
    const float4* wv = (const float4*)(W_l2h + (size_t)j * ZZ);
    float s = 0.f;
#pragma unroll 8
    for (int k = 0; k < ZZ / 4; ++k) {
        float4 a = zv[k], b = wv[k];
        s += a.x * b.x + a.y * b.y + a.z * b.z + a.w * b.w;
    }
    h0[idx] = s + b_l2h[j];
}

// ---------------- per-row logsumexp merge (one wave per row, nt <= 64) ----------------
__global__ __launch_bounds__(64) void lse_reduce(
    const float* __restrict__ pm, const float* __restrict__ ps,
    float* __restrict__ lse, int nt)
{
    int row = blockIdx.x;
    int l = threadIdx.x;
    float m = (l < nt) ? pm[(size_t)row * nt + l] : -3.0e38f;
    float s = (l < nt) ? ps[(size_t)row * nt + l] : 0.f;
    for (int mk = 1; mk <= 32; mk <<= 1) {
        float m2 = __shfl_xor(m, mk);
        float s2 = __shfl_xor(s, mk);
        float mn = fmaxf(m, m2);
        s = s * __expf(m - mn) + s2 * __expf(m2 - mn);
        m = mn;
    }
    if (l == 0) lse[row] = m + logf(s);
}

extern "C" void kernel_launch(void* const* d_in, const int* in_sizes, int n_in,
                              void* d_out, int out_size, void* d_ws, size_t ws_size,
                              hipStream_t stream)
{
    const int*           nodes     = (const int*)d_in[0];
    const unsigned char* edges_raw = (const unsigned char*)d_in[1];
    const float* emb    = (const float*)d_in[2];
    const float* ecWih  = (const float*)d_in[3];
    const float* ecWhh  = (const float*)d_in[4];
    const float* ecbih  = (const float*)d_in[5];
    const float* ecbhh  = (const float*)d_in[6];
    const float* esWih  = (const float*)d_in[7];
    const float* esWhh  = (const float*)d_in[8];
    const float* esbih  = (const float*)d_in[9];
    const float* esbhh  = (const float*)d_in[10];
    const float* dcWih  = (const float*)d_in[11];
    const float* dcWhh  = (const float*)d_in[12];
    const float* dcbih  = (const float*)d_in[13];
    const float* dcbhh  = (const float*)d_in[14];
    const float* dsWih  = (const float*)d_in[15];
    const float* dsWhh  = (const float*)d_in[16];
    const float* dsbih  = (const float*)d_in[17];
    const float* dsbhh  = (const float*)d_in[18];
    const float* W_mean = (const float*)d_in[19];
    const float* b_mean = (const float*)d_in[20];
    const float* W_logv = (const float*)d_in[21];
    const float* b_logv = (const float*)d_in[22];
    const float* W_l2h  = (const float*)d_in[23];
    const float* b_l2h  = (const float*)d_in[24];
    const float* W_out  = (const float*)d_in[25];
    const float* b_out  = (const float*)d_in[26];
    const float* enc_init = (const float*)d_in[27];
    const float* eps    = (const float*)d_in[28];

    float* out      = (float*)d_out;
    float* out_mean = out + (size_t)TT * DD * VV;
    float* out_logv = out_mean + DD * ZZ;
    float* out_z    = out_logv + DD * ZZ;
    float* gi       = out;                  // scratch in logits region: [4096][3072]

    char* ws = (char*)d_ws;
    float*          hb0     = (float*)(ws + 0);                  // 128KB
    float*          hb1     = (float*)(ws + 131072);             // 128KB
    __hip_bfloat16* outs_pk = (__hip_bfloat16*)(ws + 262144);    // 2MB packed
    __hip_bfloat16* Ap      = (__hip_bfloat16*)(ws + 2359296);   // 2MB packed
    __hip_bfloat16* Wp      = (__hip_bfloat16*)(ws + 4456448);   // 16MB packed
    __hip_bfloat16* Bp_all  = (__hip_bfloat16*)(ws + 20840448);  // 1.5MB packed
    float*          pm      = (float*)(ws + 22413312);           // 800KB
    float*          ps      = (float*)(ws + 23232512);           // 800KB
    float*          lse     = (float*)(ws + 24051712);           // 16KB
    unsigned char*  ecan    = (unsigned char*)(ws + 24068096);   // 4KB

    edge_canon_k<<<1, 256, 0, stream>>>(edges_raw, ecan);
    // pack W_out (f32 -> bf16 fragment-linear), 2000 n16-blocks = 1,024,000 chunks
    pack_frag<<<4000, 256, 0, stream>>>(W_out, Wp, 2000 * 8 * 64);
    // pack the 4 input-side GRU weight matrices (each 768 rows = 48 blocks)
    pack_frag<<<96, 256, 0, stream>>>(ecWih, Bp_all + 0 * (size_t)48 * 4096, 48 * 8 * 64);
    pack_frag<<<96, 256, 0, stream>>>(esWih, Bp_all + 1 * (size_t)48 * 4096, 48 * 8 * 64);
    pack_frag<<<96, 256, 0, stream>>>(dcWih, Bp_all + 2 * (size_t)48 * 4096, 48 * 8 * 64);
    pack_frag<<<96, 256, 0, stream>>>(dsWih, Bp_all + 3 * (size_t)48 * 4096, 48 * 8 * 64);
    gather_pack<<<512, 256, 0, stream>>>(nodes, emb, Ap);

    // gi[4096][3072] = emb-gather x [all 4 W_ih]^T  (into d_out scratch)
    gemm_rs<true, false, false, false><<<dim3(64, 6), 256, 0, stream>>>(
        Ap, Bp_all, 3072, 8, 6, nullptr, nullptr, gi, nullptr, nullptr);

    // encoder
    for (int t = 0; t < TT; ++t) {
        const float* hin = (t == 0) ? enc_init : ((t & 1) ? hb0 : hb1);
        float* hout = (t & 1) ? hb1 : hb0;
        gru_step4<<<dim3(8, 16), 256, 0, stream>>>(
            ecan + t * DD, gi + (size_t)t * DD * 3072, 0,
            ecWhh, ecbih, ecbhh, esWhh, esbih, esbhh,
            hin, hout, (__hip_bfloat16*)nullptr, t);
    }
    latent_k<<<128, 256, 0, stream>>>(hb1, W_mean, b_mean, W_logv, b_logv, eps,
                                      out_mean, out_logv, out_z);
    h0_k<<<128, 256, 0, stream>>>(out_z, W_l2h, b_l2h, hb0);

    // decoder (writes outs directly in packed-fragment layout)
    for (int t = 0; t < TT; ++t) {
        const float* hin = (t & 1) ? hb1 : hb0;
        float* hout = (t & 1) ? hb0 : hb1;
        gru_step4<<<dim3(8, 16), 256, 0, stream>>>(
            ecan + t * DD, gi + (size_t)t * DD * 3072, 1536,
            dcWhh, dcbih, dcbhh, dsWhh, dsbih, dsbhh,
            hin, hout, outs_pk, t);
    }

    // pass A: LSE partials only (no C write)
    gemm_rs<false, true, true, false><<<dim3(64, NTL), 256, 0, stream>>>(
        outs_pk, Wp, VV, 10, NTL, b_out, nullptr, nullptr, pm, ps);
    lse_reduce<<<4096, 64, 0, stream>>>(pm, ps, lse, NTL);
    // pass B: recompute, write logp = logits - lse
    gemm_rs<true, true, false, true><<<dim3(64, NTL), 256, 0, stream>>>(
        outs_pk, Wp, VV, 10, NTL, b_out, lse, out, nullptr, nullptr);
}

// Round 5
// 945.991 us; speedup vs baseline: 2.5636x; 2.5636x over previous
//
#include <hip/hip_runtime.h>
#include <hip/hip_bf16.h>

#define TT 32
#define DD 128
#define HH 256
#define VV 32000
#define ZZ 256
#define NTL 50            // n-slabs for V-GEMM (50 x 640 = 32000)

typedef __attribute__((ext_vector_type(8))) short bf16x8;
typedef __attribute__((ext_vector_type(4))) float f32x4;
typedef _Float16 h2v __attribute__((ext_vector_type(2)));

static __device__ inline unsigned short f2bf(float x) {
    __hip_bfloat16 h = __float2bfloat16(x);
    return *(unsigned short*)&h;
}

static __device__ inline float fdot2u(unsigned int w, unsigned int h, float acc) {
#if __has_builtin(__builtin_amdgcn_fdot2)
    return __builtin_amdgcn_fdot2(__builtin_bit_cast(h2v, w),
                                  __builtin_bit_cast(h2v, h), acc, false);
#else
    h2v a = __builtin_bit_cast(h2v, w), b = __builtin_bit_cast(h2v, h);
    return acc + (float)a[0] * (float)b[0] + (float)a[1] * (float)b[1];
#endif
}

// ---------------- edges canonicalizer (bool-vs-int32 layout detect) ----------------
__global__ void edge_canon_k(const unsigned char* __restrict__ eb,
                             unsigned char* __restrict__ canon)
{
    __shared__ int flag;
    if (threadIdx.x == 0) flag = 0;
    __syncthreads();
    int acc = 0;
    for (int i = threadIdx.x; i < TT * DD; i += 256)
        if (i & 3) acc |= eb[i];
    if (acc) atomicOr(&flag, 1);
    __syncthreads();
    const bool is_i32 = (flag == 0);
    for (int i = threadIdx.x; i < TT * DD; i += 256)
        canon[i] = is_i32 ? eb[4 * (size_t)i] : eb[i];
}

// ---------------- pack f32 [nrow16*16][256] -> fragment-linear bf16 ----------------
__global__ __launch_bounds__(256) void pack_frag(
    const float* __restrict__ src, __hip_bfloat16* __restrict__ dst, int nchunks_total)
{
    int i = blockIdx.x * 256 + threadIdx.x;
    if (i >= nchunks_total) return;
    int lane = i & 63, ks = (i >> 6) & 7, j = i >> 9;
    int g = lane >> 4, c = lane & 15;
    const float* s = src + (size_t)(j * 16 + c) * HH + ks * 32 + g * 8;
    float4 v0 = *(const float4*)s;
    float4 v1 = *(const float4*)(s + 4);
    bf16x8 o;
    o[0] = (short)f2bf(v0.x); o[1] = (short)f2bf(v0.y);
    o[2] = (short)f2bf(v0.z); o[3] = (short)f2bf(v0.w);
    o[4] = (short)f2bf(v1.x); o[5] = (short)f2bf(v1.y);
    o[6] = (short)f2bf(v1.z); o[7] = (short)f2bf(v1.w);
    *(bf16x8*)(dst + (size_t)i * 8) = o;
}

// ---------------- gather emb rows by token -> packed fragment A [4096][256] ----------------
__global__ __launch_bounds__(256) void gather_pack(
    const int* __restrict__ nodes, const float* __restrict__ emb,
    __hip_bfloat16* __restrict__ dst)
{
    int i = blockIdx.x * 256 + threadIdx.x;      // 131072 chunks
    int lane = i & 63, ks = (i >> 6) & 7, j = i >> 9;
    int g = lane >> 4, c = lane & 15;
    int row = j * 16 + c;
    int tok = nodes[row];
    const float* s = emb + (size_t)tok * HH + ks * 32 + g * 8;
    float4 v0 = *(const float4*)s;
    float4 v1 = *(const float4*)(s + 4);
    bf16x8 o;
    o[0] = (short)f2bf(v0.x); o[1] = (short)f2bf(v0.y);
    o[2] = (short)f2bf(v0.z); o[3] = (short)f2bf(v0.w);
    o[4] = (short)f2bf(v1.x); o[5] = (short)f2bf(v1.y);
    o[6] = (short)f2bf(v1.z); o[7] = (short)f2bf(v1.w);
    *(bf16x8*)(dst + (size_t)i * 8) = o;
}

// ---------------- pack Whh f32 [768][256] -> transposed f16 [64 k4][768 j][4] ----------------
__global__ __launch_bounds__(256) void pack_whh_t(
    const float* __restrict__ src, uint2* __restrict__ dst)
{
    int i = blockIdx.x * 256 + threadIdx.x;   // 49152
    if (i >= 64 * 768) return;
    int j = i % 768, k4 = i / 768;
    float4 v = *(const float4*)(src + (size_t)j * HH + k4 * 4);
    h2v p0; p0[0] = (_Float16)v.x; p0[1] = (_Float16)v.y;
    h2v p1; p1[0] = (_Float16)v.z; p1[1] = (_Float16)v.w;
    uint2 o;
    o.x = __builtin_bit_cast(unsigned int, p0);
    o.y = __builtin_bit_cast(unsigned int, p1);
    dst[i] = o;
}

// ---------------- transpose 256x256 f32 (latent weights) ----------------
__global__ __launch_bounds__(256) void pack_lat_t(
    const float* __restrict__ src, float* __restrict__ dst)
{
    int i = blockIdx.x * 256 + threadIdx.x;   // 65536
    int j = i & 255, k = i >> 8;
    dst[(size_t)k * 256 + j] = src[(size_t)j * 256 + k];
}

// ============ register-stationary GEMM, packed operands ============
template<bool WRITE_C, bool HAS_BIAS, bool LSE_PARTIAL, bool LSE_SUB>
__global__ __launch_bounds__(256, 4) void gemm_rs(
    const __hip_bfloat16* __restrict__ A,
    const __hip_bfloat16* __restrict__ B,
    int ldc, int nchunks, int ntiles,
    const float* __restrict__ bias,
    const float* __restrict__ lse,
    float* __restrict__ C,
    float* __restrict__ pm, float* __restrict__ ps)
{
    __shared__ float lds_st[WRITE_C ? (4 * 16 * 68) : 1];

    const int tid  = threadIdx.x;
    const int w    = tid >> 6;
    const int lane = tid & 63;
    const int g    = lane >> 4;
    const int c    = lane & 15;
    const int m0   = blockIdx.x * 64;
    const int row16 = m0 + w * 16;
    const int n0   = blockIdx.y * (nchunks * 64);
    const int jb0  = n0 >> 4;

    bf16x8 a[8];
    {
        const __hip_bfloat16* ap = A + (((size_t)(row16 >> 4) * 8) * 64 + lane) * 8;
#pragma unroll
        for (int ks = 0; ks < 8; ++ks) a[ks] = *(const bf16x8*)(ap + ks * 512);
    }

    float mrun[4], srun[4];
#pragma unroll
    for (int r = 0; r < 4; ++r) { mrun[r] = -3.0e38f; srun[r] = 0.f; }

    float lsev[4];
    if (LSE_SUB) {
#pragma unroll
        for (int r = 0; r < 4; ++r) lsev[r] = lse[row16 + 4 * g + r];
    }

    for (int nc = 0; nc < nchunks; ++nc) {
        const int nb = n0 + nc * 64;
        const __hip_bfloat16* bp = B + (((size_t)(jb0 + nc * 4) * 8) * 64 + lane) * 8;

        f32x4 acc[4];
#pragma unroll
        for (int nf = 0; nf < 4; ++nf) acc[nf] = (f32x4){0.f, 0.f, 0.f, 0.f};

#pragma unroll
        for (int ks = 0; ks < 8; ++ks) {
            bf16x8 b0 = *(const bf16x8*)(bp + (0 * 8 + ks) * 512);
            bf16x8 b1 = *(const bf16x8*)(bp + (1 * 8 + ks) * 512);
            bf16x8 b2 = *(const bf16x8*)(bp + (2 * 8 + ks) * 512);
            bf16x8 b3 = *(const bf16x8*)(bp + (3 * 8 + ks) * 512);
            acc[0] = __builtin_amdgcn_mfma_f32_16x16x32_bf16(a[ks], b0, acc[0], 0, 0, 0);
            acc[1] = __builtin_amdgcn_mfma_f32_16x16x32_bf16(a[ks], b1, acc[1], 0, 0, 0);
            acc[2] = __builtin_amdgcn_mfma_f32_16x16x32_bf16(a[ks], b2, acc[2], 0, 0, 0);
            acc[3] = __builtin_amdgcn_mfma_f32_16x16x32_bf16(a[ks], b3, acc[3], 0, 0, 0);
        }

        float bv[4] = {0.f, 0.f, 0.f, 0.f};
        if (HAS_BIAS) {
#pragma unroll
            for (int nf = 0; nf < 4; ++nf) bv[nf] = bias[nb + nf * 16 + c];
        }

        if (LSE_PARTIAL) {
#pragma unroll
            for (int r = 0; r < 4; ++r) {
                float l0 = acc[0][r] + bv[0];
                float l1 = acc[1][r] + bv[1];
                float l2 = acc[2][r] + bv[2];
                float l3 = acc[3][r] + bv[3];
                float mc = fmaxf(fmaxf(l0, l1), fmaxf(l2, l3));
                float mn = fmaxf(mrun[r], mc);
                srun[r] = srun[r] * __expf(mrun[r] - mn)
                        + __expf(l0 - mn) + __expf(l1 - mn)
                        + __expf(l2 - mn) + __expf(l3 - mn);
                mrun[r] = mn;
            }
        }

        if (WRITE_C) {
            const int base = w * (16 * 68);
#pragma unroll
            for (int nf = 0; nf < 4; ++nf)
#pragma unroll
                for (int r = 0; r < 4; ++r) {
                    float v = acc[nf][r] + bv[nf];
                    if (LSE_SUB) v -= lsev[r];
                    lds_st[base + (4 * g + r) * 68 + nf * 16 + c] = v;
                }
#pragma unroll
            for (int i = 0; i < 4; ++i) {
                int lr = i * 4 + g;
                float4 v = *(const float4*)&lds_st[base + lr * 68 + c * 4];
                *(float4*)(C + (size_t)(row16 + lr) * ldc + nb + c * 4) = v;
            }
        }
    }

    if (LSE_PARTIAL) {
#pragma unroll
        for (int r = 0; r < 4; ++r) {
            float m = mrun[r], s = srun[r];
#pragma unroll
            for (int mk = 1; mk <= 8; mk <<= 1) {
                float m2 = __shfl_xor(m, mk);
                float s2 = __shfl_xor(s, mk);
                float mn = fmaxf(m, m2);
                s = s * __expf(m - mn) + s2 * __expf(m2 - mn);
                m = mn;
            }
            if (c == 0) {
                int row = row16 + 4 * g + r;
                pm[(size_t)row * ntiles + blockIdx.y] = m;
                ps[(size_t)row * ntiles + blockIdx.y] = s;
            }
        }
    }
}

// ============ fused full recurrence: enc 32 steps -> latent -> h0 -> dec 32 steps ============
// One block per tree position d (row-local recurrence!). 768 threads = 12 waves.
// Thread t owns gate-row t of the h-side GEMV; weights streamed from L2 in
// transposed-packed f16 (512B contiguous per wave-load), dot via v_dot2_f32_f16.
__global__ __launch_bounds__(768) void rnn_fused(
    const unsigned char* __restrict__ ecan,
    const float* __restrict__ gi,          // [4096][3072] input-side gates
    const uint2* __restrict__ Wt,          // [4][49152] : ec, es, dc, ds
    const float* __restrict__ ecbih, const float* __restrict__ ecbhh,
    const float* __restrict__ esbih, const float* __restrict__ esbhh,
    const float* __restrict__ dcbih, const float* __restrict__ dcbhh,
    const float* __restrict__ dsbih, const float* __restrict__ dsbhh,
    const float* __restrict__ WmT, const float* __restrict__ WlT,
    const float* __restrict__ WhT,
    const float* __restrict__ b_mean, const float* __restrict__ b_logv,
    const float* __restrict__ b_l2h,
    const float* __restrict__ enc_init, const float* __restrict__ eps,
    float* __restrict__ out_mean, float* __restrict__ out_logv,
    float* __restrict__ out_z,
    __hip_bfloat16* __restrict__ outs_pk)
{
    const int d = blockIdx.x;
    const int t = threadIdx.x;

    __shared__ float h[HH];
    __shared__ unsigned int hp[HH / 2];   // h as packed half2
    __shared__ float gh[768];
    __shared__ float zl[ZZ];

    if (t < HH) h[t] = enc_init[(size_t)d * HH + t];
    __syncthreads();
    if (t < HH / 2) {
        h2v p; p[0] = (_Float16)h[2 * t]; p[1] = (_Float16)h[2 * t + 1];
        hp[t] = __builtin_bit_cast(unsigned int, p);
    }
    __syncthreads();

    for (int phase = 0; phase < 2; ++phase) {
        const float* bihc = phase ? dcbih : ecbih;
        const float* bhhc = phase ? dcbhh : ecbhh;
        const float* bihs = phase ? dsbih : esbih;
        const float* bhhs = phase ? dsbhh : esbhh;

        for (int st = 0; st < TT; ++st) {
            const bool e = ecan[st * DD + d] != 0;
            const uint2* W = Wt + (size_t)(phase * 2 + (e ? 0 : 1)) * 49152 + t;
            float acc = 0.f;
#pragma unroll 8
            for (int k4 = 0; k4 < 64; ++k4) {
                uint2 w = W[k4 * 768];
                uint2 hh = *(const uint2*)&hp[2 * k4];   // LDS broadcast
                acc = fdot2u(w.x, hh.x, acc);
                acc = fdot2u(w.y, hh.y, acc);
            }
            gh[t] = acc;
            __syncthreads();

            if (t < HH) {
                const float* bih = e ? bihc : bihs;
                const float* bhh = e ? bhhc : bhhs;
                const float* gr = gi + (size_t)(st * DD + d) * 3072
                                + phase * 1536 + (e ? 0 : 768);
                float ir  = gr[t]          + bih[t];
                float iz  = gr[t + HH]     + bih[t + HH];
                float in_ = gr[t + 2 * HH] + bih[t + 2 * HH];
                float hr  = gh[t]          + bhh[t];
                float hz  = gh[t + HH]     + bhh[t + HH];
                float hn  = gh[t + 2 * HH] + bhh[t + 2 * HH];
                float rg = 1.f / (1.f + __expf(-(ir + hr)));
                float zg = 1.f / (1.f + __expf(-(iz + hz)));
                float nn = tanhf(in_ + rg * hn);
                float hnew = (1.f - zg) * nn + zg * h[t];
                h[t] = hnew;
                if (phase) {
                    size_t idx = ((((size_t)st * 8 + (d >> 4)) * 8 + (t >> 5)) * 64
                                 + (((t >> 3) & 3) * 16 + (d & 15))) * 8 + (t & 7);
                    outs_pk[idx] = __float2bfloat16(hnew);
                }
            }
            __syncthreads();
            if (t < HH / 2) {
                h2v p; p[0] = (_Float16)h[2 * t]; p[1] = (_Float16)h[2 * t + 1];
                hp[t] = __builtin_bit_cast(unsigned int, p);
            }
            __syncthreads();
        }

        if (phase == 0) {
            // latent head, all row-local: mean (t<256), logv (256<=t<512)
            if (t < 512) {
                int zi = t & 255;
                const float* WT = (t < 256) ? WmT : WlT;
                float s = 0.f;
#pragma unroll 8
                for (int k = 0; k < HH; ++k) s += h[k] * WT[k * ZZ + zi];
                if (t < 256) {
                    float mean = s + b_mean[zi];
                    out_mean[(size_t)d * ZZ + zi] = mean;
                    gh[zi] = mean;
                } else {
                    float logv = s + b_logv[zi];
                    out_logv[(size_t)d * ZZ + zi] = logv;
                    gh[256 + zi] = logv;
                }
            }
            __syncthreads();
            if (t < ZZ) {
                float zv = eps[(size_t)d * ZZ + t] * __expf(0.5f * gh[256 + t]) + gh[t];
                out_z[(size_t)d * ZZ + t] = zv;
                zl[t] = zv;
            }
            __syncthreads();
            if (t < HH) {
                float s = 0.f;
#pragma unroll 8
                for (int k = 0; k < ZZ; ++k) s += zl[k] * WhT[k * HH + t];
                h[t] = s + b_l2h[t];
            }
            __syncthreads();
            if (t < HH / 2) {
                h2v p; p[0] = (_Float16)h[2 * t]; p[1] = (_Float16)h[2 * t + 1];
                hp[t] = __builtin_bit_cast(unsigned int, p);
            }
            __syncthreads();
        }
    }
}

// ---------------- per-row logsumexp merge (one wave per row, nt <= 64) ----------------
__global__ __launch_bounds__(64) void lse_reduce(
    const float* __restrict__ pm, const float* __restrict__ ps,
    float* __restrict__ lse, int nt)
{
    int row = blockIdx.x;
    int l = threadIdx.x;
    float m = (l < nt) ? pm[(size_t)row * nt + l] : -3.0e38f;
    float s = (l < nt) ? ps[(size_t)row * nt + l] : 0.f;
    for (int mk = 1; mk <= 32; mk <<= 1) {
        float m2 = __shfl_xor(m, mk);
        float s2 = __shfl_xor(s, mk);
        float mn = fmaxf(m, m2);
        s = s * __expf(m - mn) + s2 * __expf(m2 - mn);
        m = mn;
    }
    if (l == 0) lse[row] = m + logf(s);
}

extern "C" void kernel_launch(void* const* d_in, const int* in_sizes, int n_in,
                              void* d_out, int out_size, void* d_ws, size_t ws_size,
                              hipStream_t stream)
{
    const int*           nodes     = (const int*)d_in[0];
    const unsigned char* edges_raw = (const unsigned char*)d_in[1];
    const float* emb    = (const float*)d_in[2];
    const float* ecWih  = (const float*)d_in[3];
    const float* ecWhh  = (const float*)d_in[4];
    const float* ecbih  = (const float*)d_in[5];
    const float* ecbhh  = (const float*)d_in[6];
    const float* esWih  = (const float*)d_in[7];
    const float* esWhh  = (const float*)d_in[8];
    const float* esbih  = (const float*)d_in[9];
    const float* esbhh  = (const float*)d_in[10];
    const float* dcWih  = (const float*)d_in[11];
    const float* dcWhh  = (const float*)d_in[12];
    const float* dcbih  = (const float*)d_in[13];
    const float* dcbhh  = (const float*)d_in[14];
    const float* dsWih  = (const float*)d_in[15];
    const float* dsWhh  = (const float*)d_in[16];
    const float* dsbih  = (const float*)d_in[17];
    const float* dsbhh  = (const float*)d_in[18];
    const float* W_mean = (const float*)d_in[19];
    const float* b_mean = (const float*)d_in[20];
    const float* W_logv = (const float*)d_in[21];
    const float* b_logv = (const float*)d_in[22];
    const float* W_l2h  = (const float*)d_in[23];
    const float* b_l2h  = (const float*)d_in[24];
    const float* W_out  = (const float*)d_in[25];
    const float* b_out  = (const float*)d_in[26];
    const float* enc_init = (const float*)d_in[27];
    const float* eps    = (const float*)d_in[28];

    float* out      = (float*)d_out;
    float* out_mean = out + (size_t)TT * DD * VV;
    float* out_logv = out_mean + DD * ZZ;
    float* out_z    = out_logv + DD * ZZ;
    float* gi       = out;                  // scratch in logits region: [4096][3072]

    char* ws = (char*)d_ws;
    __hip_bfloat16* outs_pk = (__hip_bfloat16*)(ws + 0);         // 2MB packed
    __hip_bfloat16* Ap      = (__hip_bfloat16*)(ws + 2097152);   // 2MB packed
    __hip_bfloat16* Wp      = (__hip_bfloat16*)(ws + 4194304);   // 16MB packed W_out
    __hip_bfloat16* Bp_all  = (__hip_bfloat16*)(ws + 20971520);  // 1.5MB packed Wih x4
    uint2*          Wt      = (uint2*)(ws + 23068672);           // 1.5MB f16-transposed Whh x4
    float*          WmT     = (float*)(ws + 25165824);           // 256KB
    float*          WlT     = (float*)(ws + 25427968);           // 256KB
    float*          WhT     = (float*)(ws + 25690112);           // 256KB
    float*          pm      = (float*)(ws + 25952256);           // 800KB
    float*          ps      = (float*)(ws + 26771456);           // 800KB
    float*          lse     = (float*)(ws + 27590656);           // 16KB
    unsigned char*  ecan    = (unsigned char*)(ws + 27607040);   // 4KB

    edge_canon_k<<<1, 256, 0, stream>>>(edges_raw, ecan);
    pack_frag<<<4000, 256, 0, stream>>>(W_out, Wp, 2000 * 8 * 64);
    pack_frag<<<96, 256, 0, stream>>>(ecWih, Bp_all + 0 * (size_t)48 * 4096, 48 * 8 * 64);
    pack_frag<<<96, 256, 0, stream>>>(esWih, Bp_all + 1 * (size_t)48 * 4096, 48 * 8 * 64);
    pack_frag<<<96, 256, 0, stream>>>(dcWih, Bp_all + 2 * (size_t)48 * 4096, 48 * 8 * 64);
    pack_frag<<<96, 256, 0, stream>>>(dsWih, Bp_all + 3 * (size_t)48 * 4096, 48 * 8 * 64);
    pack_whh_t<<<192, 256, 0, stream>>>(ecWhh, Wt + 0 * (size_t)49152);
    pack_whh_t<<<192, 256, 0, stream>>>(esWhh, Wt + 1 * (size_t)49152);
    pack_whh_t<<<192, 256, 0, stream>>>(dcWhh, Wt + 2 * (size_t)49152);
    pack_whh_t<<<192, 256, 0, stream>>>(dsWhh, Wt + 3 * (size_t)49152);
    pack_lat_t<<<256, 256, 0, stream>>>(W_mean, WmT);
    pack_lat_t<<<256, 256, 0, stream>>>(W_logv, WlT);
    pack_lat_t<<<256, 256, 0, stream>>>(W_l2h, WhT);
    gather_pack<<<512, 256, 0, stream>>>(nodes, emb, Ap);

    // gi[4096][3072] = emb-gather x [all 4 W_ih]^T  (into d_out scratch)
    gemm_rs<true, false, false, false><<<dim3(64, 6), 256, 0, stream>>>(
        Ap, Bp_all, 3072, 8, 6, nullptr, nullptr, gi, nullptr, nullptr);

    // fused recurrence: encoder -> latent -> h0 -> decoder (writes packed outs)
    rnn_fused<<<DD, 768, 0, stream>>>(
        ecan, gi, Wt,
        ecbih, ecbhh, esbih, esbhh, dcbih, dcbhh, dsbih, dsbhh,
        WmT, WlT, WhT, b_mean, b_logv, b_l2h,
        enc_init, eps, out_mean, out_logv, out_z, outs_pk);

    // pass A: LSE partials only (no C write)
    gemm_rs<false, true, true, false><<<dim3(64, NTL), 256, 0, stream>>>(
        outs_pk, Wp, VV, 10, NTL, b_out, nullptr, nullptr, pm, ps);
    lse_reduce<<<4096, 64, 0, stream>>>(pm, ps, lse, NTL);
    // pass B: recompute, write logp = logits - lse
    gemm_rs<true, true, false, true><<<dim3(64, NTL), 256, 0, stream>>>(
        outs_pk, Wp, VV, 10, NTL, b_out, lse, out, nullptr, nullptr);
}